// Round 5
// baseline (1086.391 us; speedup 1.0000x reference)
//
#include <hip/hip_runtime.h>
#include <cstdint>

#define SEQ 512
#define BATCH 2048
#define HID 50
#define BB 4              // real batches per block (N padded to 16)
#define NTHR 256          // 4 waves
#define NBLK (BATCH / BB) // 512 blocks -> 2 per CU
#define NT 13             // gate-row tiles of 16 (200 -> 208, permuted rows)
#define S1H 72            // u1 row stride (halves): [x(4)|h1(50)|zero..64|pad..72]
#define S2H 136           // u2 row stride: [relu(h1)(50)|h2(50)|zero..128|pad..136]

typedef _Float16 f16;
typedef _Float16 v8h __attribute__((ext_vector_type(8)));
typedef float    v4f __attribute__((ext_vector_type(4)));

__device__ __forceinline__ float sigf(float x) {
    return __builtin_amdgcn_rcpf(1.0f + __expf(-x));
}
__device__ __forceinline__ float tanhf_(float x) {
    return 1.0f - 2.0f * __builtin_amdgcn_rcpf(1.0f + __expf(2.0f * x));
}

// Row permutation: tile t, in-tile row rho -> orig W row (rho%4)*50 + t*4 + rho/4.
// C layout (col=lane&15, row=(lane>>4)*4+reg) then gives lane (q,b):
// regs = [i,f,g,o] of unit u = t*4+q, batch b  -> cell update is lane-local.

__global__ __launch_bounds__(NTHR, 2) void lstm2_fused(
    const float* __restrict__ x,
    const float* __restrict__ w_ih1, const float* __restrict__ w_hh1,
    const float* __restrict__ b_ih1, const float* __restrict__ b_hh1,
    const float* __restrict__ w_ih2, const float* __restrict__ w_hh2,
    const float* __restrict__ b_ih2, const float* __restrict__ b_hh2,
    const float* __restrict__ w_fc, const float* __restrict__ b_fc,
    float* __restrict__ out)
{
    __shared__ __align__(16) f16 u1h[2][16 * S1H];
    __shared__ __align__(16) f16 u2h[2][16 * S2H];
    __shared__ float fcw[16];

    const int tid  = threadIdx.x;
    const int wv   = tid >> 6;      // 0..3
    const int lane = tid & 63;
    const int mb   = lane & 15;     // A-load: row-in-tile | B-load & C: batch col
    const int q    = lane >> 4;     // quad
    const int bbase = blockIdx.x * BB;

    // ---- weight-stationary A-fragments (permuted rows), biases, wfc ----
    v8h A1[4][2];            // [tile][ktile]  L1: K=54 -> 2 ktiles of 32
    v8h A2[4][4];            // L2: K=100 -> 4 ktiles
    float b1r[4][4], b2r[4][4], wf[4];
#pragma unroll
    for (int i = 0; i < 4; ++i) {
        const int tt = wv + 4 * i;
        const bool tv = (tt < NT);
        const int ru = tt * 4 + (mb >> 2);     // A-row: hidden unit
        const bool rv = tv && (ru < HID);
        const int R = (mb & 3) * HID + ru;     // original W row (gate-major)
#pragma unroll
        for (int kt = 0; kt < 2; ++kt) {
            v8h f;
#pragma unroll
            for (int j = 0; j < 8; ++j) {
                const int kk = kt * 32 + q * 8 + j;
                float v = 0.0f;
                if (rv) {
                    if (kk < 4) v = w_ih1[R * 4 + kk];
                    else if (kk < 54) v = w_hh1[R * HID + (kk - 4)];
                }
                f[j] = (f16)v;
            }
            A1[i][kt] = f;
        }
#pragma unroll
        for (int kt = 0; kt < 4; ++kt) {
            v8h f;
#pragma unroll
            for (int j = 0; j < 8; ++j) {
                const int kk = kt * 32 + q * 8 + j;
                float v = 0.0f;
                if (rv) {
                    if (kk < HID) v = w_ih2[R * HID + kk];
                    else if (kk < 2 * HID) v = w_hh2[R * HID + (kk - HID)];
                }
                f[j] = (f16)v;
            }
            A2[i][kt] = f;
        }
        // update-phase constants use C-layout unit uc = tt*4 + q
        const int uc = tt * 4 + q;
        const bool cv = tv && (uc < HID);
#pragma unroll
        for (int g = 0; g < 4; ++g) {
            b1r[i][g] = cv ? (b_ih1[g * HID + uc] + b_hh1[g * HID + uc]) : 0.0f;
            b2r[i][g] = cv ? (b_ih2[g * HID + uc] + b_hh2[g * HID + uc]) : 0.0f;
        }
        wf[i] = cv ? w_fc[uc] : 0.0f;
    }

    // ---- LDS init (both parity buffers zero) ----
    for (int idx = tid; idx < 2 * 16 * S1H; idx += NTHR) ((f16*)u1h)[idx] = (f16)0.0f;
    for (int idx = tid; idx < 2 * 16 * S2H; idx += NTHR) ((f16*)u2h)[idx] = (f16)0.0f;
    const float bfc = b_fc[0];
    float c1r[4] = {0.f, 0.f, 0.f, 0.f};
    float c2r[4] = {0.f, 0.f, 0.f, 0.f};
    __syncthreads();
    if (wv == 0 && lane < BB) {    // x(0) -> u1 buf 0
        const float4 x0 = *reinterpret_cast<const float4*>(x + (size_t)(bbase + lane) * 4);
        f16 p[4] = {(f16)x0.x, (f16)x0.y, (f16)x0.z, (f16)x0.w};
        *reinterpret_cast<uint2*>(&u1h[0][lane * S1H]) = *reinterpret_cast<uint2*>(p);
    }
    __syncthreads();

#pragma unroll 1
    for (int t = 0; t < SEQ; ++t) {
        // x(t+1) prefetch (wave 0, lanes 0..3)
        float4 xr;
        if (wv == 0 && lane < BB) {
            const int tn = (t + 1 < SEQ) ? t + 1 : SEQ - 1;
            xr = *reinterpret_cast<const float4*>(
                x + ((size_t)tn * BATCH + bbase + lane) * 4);
        }

        // ---------------- phase 1: L1 gates (MFMA) + lane-local update ----------------
        const f16* u1p = u1h[t & 1];
        f16* u1n = u1h[(t + 1) & 1];
        f16* u2c = u2h[t & 1];
        const v8h B0 = *reinterpret_cast<const v8h*>(&u1p[mb * S1H + q * 8]);
        const v8h B1 = *reinterpret_cast<const v8h*>(&u1p[mb * S1H + 32 + q * 8]);
#pragma unroll
        for (int i = 0; i < 4; ++i) {
            const int tt = wv + 4 * i;
            if (tt < NT) {
                v4f acc = {0.f, 0.f, 0.f, 0.f};
                acc = __builtin_amdgcn_mfma_f32_16x16x32_f16(A1[i][0], B0, acc, 0, 0, 0);
                acc = __builtin_amdgcn_mfma_f32_16x16x32_f16(A1[i][1], B1, acc, 0, 0, 0);
                const float ig = sigf(acc[0] + b1r[i][0]);
                const float fg = sigf(acc[1] + b1r[i][1]);
                const float cg = tanhf_(acc[2] + b1r[i][2]);
                const float og = sigf(acc[3] + b1r[i][3]);
                c1r[i] = fg * c1r[i] + ig * cg;
                const float h1 = og * tanhf_(c1r[i]);
                const int uc = tt * 4 + q;
                if (uc < HID && mb < BB) {
                    u1n[mb * S1H + 4 + uc] = (f16)h1;                 // next-step recurrent
                    u2c[mb * S2H + uc] = (f16)fmaxf(h1, 0.0f);        // this-step L2 input
                }
            }
        }
        if (wv == 0 && lane < BB) {   // x(t+1) into next parity buffer
            f16 p[4] = {(f16)xr.x, (f16)xr.y, (f16)xr.z, (f16)xr.w};
            *reinterpret_cast<uint2*>(&u1n[lane * S1H]) = *reinterpret_cast<uint2*>(p);
        }
        __syncthreads();  // bar X: u2c relu ready

        // ---------------- phase 2: L2 gates (MFMA) + lane-local update + FC ----------------
        f16* u2n = u2h[(t + 1) & 1];
        const v8h C0 = *reinterpret_cast<const v8h*>(&u2c[mb * S2H + q * 8]);
        const v8h C1 = *reinterpret_cast<const v8h*>(&u2c[mb * S2H + 32 + q * 8]);
        const v8h C2 = *reinterpret_cast<const v8h*>(&u2c[mb * S2H + 64 + q * 8]);
        const v8h C3 = *reinterpret_cast<const v8h*>(&u2c[mb * S2H + 96 + q * 8]);
        float fcp = 0.0f;
#pragma unroll
        for (int i = 0; i < 4; ++i) {
            const int tt = wv + 4 * i;
            if (tt < NT) {
                v4f acc = {0.f, 0.f, 0.f, 0.f};
                acc = __builtin_amdgcn_mfma_f32_16x16x32_f16(A2[i][0], C0, acc, 0, 0, 0);
                acc = __builtin_amdgcn_mfma_f32_16x16x32_f16(A2[i][1], C1, acc, 0, 0, 0);
                acc = __builtin_amdgcn_mfma_f32_16x16x32_f16(A2[i][2], C2, acc, 0, 0, 0);
                acc = __builtin_amdgcn_mfma_f32_16x16x32_f16(A2[i][3], C3, acc, 0, 0, 0);
                const float ig = sigf(acc[0] + b2r[i][0]);
                const float fg = sigf(acc[1] + b2r[i][1]);
                const float cg = tanhf_(acc[2] + b2r[i][2]);
                const float og = sigf(acc[3] + b2r[i][3]);
                c2r[i] = fg * c2r[i] + ig * cg;
                const float h2 = og * tanhf_(c2r[i]);
                const int uc = tt * 4 + q;
                if (uc < HID) {
                    if (mb < BB) u2n[mb * S2H + HID + uc] = (f16)h2;  // next-step recurrent
                    fcp += fmaxf(h2, 0.0f) * wf[i];
                }
            }
        }
        // FC: reduce over q (xor16/32), stage per-wave partials, wave 0 finishes
        fcp += __shfl_xor(fcp, 16);
        fcp += __shfl_xor(fcp, 32);
        if (lane < BB) fcw[wv * BB + lane] = fcp;
        __syncthreads();  // bar Y: h2 + fcw ready
        if (wv == 0) {
            float v = (lane < 16) ? fcw[lane] : 0.0f;
            v += __shfl_xor(v, 4);
            v += __shfl_xor(v, 8);
            if (lane < BB) out[(size_t)t * BATCH + bbase + lane] = v + bfc;
        }
        // fcw(t) read by wave0 pre-barX(t+1); next written post-barX(t+1) — safe.
    }
}

extern "C" void kernel_launch(void* const* d_in, const int* in_sizes, int n_in,
                              void* d_out, int out_size, void* d_ws, size_t ws_size,
                              hipStream_t stream) {
    const float* X    = (const float*)d_in[0];
    const float* Wih1 = (const float*)d_in[1];
    const float* Whh1 = (const float*)d_in[2];
    const float* Bih1 = (const float*)d_in[3];
    const float* Bhh1 = (const float*)d_in[4];
    const float* Wih2 = (const float*)d_in[5];
    const float* Whh2 = (const float*)d_in[6];
    const float* Bih2 = (const float*)d_in[7];
    const float* Bhh2 = (const float*)d_in[8];
    const float* Wfc  = (const float*)d_in[9];
    const float* Bfc  = (const float*)d_in[10];
    float* out = (float*)d_out;

    lstm2_fused<<<dim3(NBLK), dim3(NTHR), 0, stream>>>(
        X, Wih1, Whh1, Bih1, Bhh1, Wih2, Whh2, Bih2, Bhh2, Wfc, Bfc, out);
}

// Round 6
// 646.174 us; speedup vs baseline: 1.6813x; 1.6813x over previous
//
#include <hip/hip_runtime.h>
#include <cstdint>

#define SEQ 512
#define BATCH 2048
#define HID 50
#define BB 8              // real batches per block (N cols padded to 16)
#define NTHR 512          // 8 waves: 0-3 = L1 group, 4-7 = L2 group
#define NBLK (BATCH / BB) // 256 blocks -> 1 per CU
#define NT 13             // gate-row tiles of 16 (200 -> 208, permuted rows)
#define S1H 72            // u1 row stride (halves): [x(4)|h1(50)|zero..64|pad..72]
#define S2H 136           // u2 row stride: [relu_h1(50)|h2(50)|zero..128|pad..136]

typedef _Float16 f16;
typedef _Float16 v8h __attribute__((ext_vector_type(8)));
typedef float    v4f __attribute__((ext_vector_type(4)));

__device__ __forceinline__ float sigf(float x) {
    return __builtin_amdgcn_rcpf(1.0f + __expf(-x));
}
__device__ __forceinline__ float tanhf_(float x) {
    return 1.0f - 2.0f * __builtin_amdgcn_rcpf(1.0f + __expf(2.0f * x));
}

// Row permutation (validated in R5): tile tt, in-tile row rho -> orig W row
// (rho%4)*50 + tt*4 + rho/4.  C layout (col=lane&15, row=(lane>>4)*4+reg)
// then puts [i,f,g,o] of unit uc=tt*4+q, batch mb in one lane's 4 C-regs.

__global__ __launch_bounds__(NTHR, 2) void lstm2_fused(
    const float* __restrict__ x,
    const float* __restrict__ w_ih1, const float* __restrict__ w_hh1,
    const float* __restrict__ b_ih1, const float* __restrict__ b_hh1,
    const float* __restrict__ w_ih2, const float* __restrict__ w_hh2,
    const float* __restrict__ b_ih2, const float* __restrict__ b_hh2,
    const float* __restrict__ w_fc, const float* __restrict__ b_fc,
    float* __restrict__ out)
{
    __shared__ __align__(16) f16 u1h[2][16 * S1H];
    __shared__ __align__(16) f16 u2h[2][16 * S2H];
    __shared__ float fcw[2][32];

    const int tid  = threadIdx.x;
    const int wv   = tid >> 6;
    const int lane = tid & 63;
    const int mb   = lane & 15;       // A-row-in-tile | B col (batch)
    const int q    = lane >> 4;       // quad
    const int bbase = blockIdx.x * BB;

    const bool grpB = (wv >= 4);      // waves 4-7: L2 (one per SIMD next to an L1 wave)
    const int  wa   = grpB ? (7 - wv) : wv;   // tile-set id; pairs SIMDk: (wa, 3-wa) -> 7 tiles max

    // ---- weight-stationary A fragments (union storage for both groups) ----
    v8h   Af[4][4];                   // L1 uses [i][0..1], L2 uses [i][0..3]
    float br[4][4], wfr[4], cst[4];
#pragma unroll
    for (int i = 0; i < 4; ++i) {
        const int tt = wa + 4 * i;
        const bool tv = (tt < NT);
        const int ru = tt * 4 + (mb >> 2);
        const bool rv = tv && (ru < HID);
        const int R = (mb & 3) * HID + ru;   // original gate-major W row
        if (!grpB) {
#pragma unroll
            for (int kt = 0; kt < 2; ++kt) {
                v8h f;
#pragma unroll
                for (int j = 0; j < 8; ++j) {
                    const int kk = kt * 32 + q * 8 + j;
                    float v = 0.0f;
                    if (rv) {
                        if (kk < 4) v = w_ih1[R * 4 + kk];
                        else if (kk < 54) v = w_hh1[R * HID + (kk - 4)];
                    }
                    f[j] = (f16)v;
                }
                Af[i][kt] = f;
            }
        } else {
#pragma unroll
            for (int kt = 0; kt < 4; ++kt) {
                v8h f;
#pragma unroll
                for (int j = 0; j < 8; ++j) {
                    const int kk = kt * 32 + q * 8 + j;
                    float v = 0.0f;
                    if (rv) {
                        if (kk < HID) v = w_ih2[R * HID + kk];
                        else if (kk < 2 * HID) v = w_hh2[R * HID + (kk - HID)];
                    }
                    f[j] = (f16)v;
                }
                Af[i][kt] = f;
            }
        }
        const int uc = tt * 4 + q;
        const bool cv = tv && (uc < HID);
#pragma unroll
        for (int g = 0; g < 4; ++g) {
            br[i][g] = cv ? (grpB ? (b_ih2[g * HID + uc] + b_hh2[g * HID + uc])
                                  : (b_ih1[g * HID + uc] + b_hh1[g * HID + uc]))
                          : 0.0f;
        }
        wfr[i] = (grpB && cv) ? w_fc[uc] : 0.0f;
        cst[i] = 0.0f;
    }
    const float bfc = b_fc[0];

    // ---- LDS init: zeros everywhere (zero-pad regions must stay zero) ----
    for (int idx = tid; idx < 2 * 16 * S1H; idx += NTHR) ((f16*)u1h)[idx] = (f16)0.0f;
    for (int idx = tid; idx < 2 * 16 * S2H; idx += NTHR) ((f16*)u2h)[idx] = (f16)0.0f;
    if (tid < 64) ((float*)fcw)[tid] = 0.0f;
    __syncthreads();
    if (tid < BB) {   // x(0) -> u1 parity 0
        const float4 x0 = *reinterpret_cast<const float4*>(x + (size_t)(bbase + tid) * 4);
        f16 p[4] = {(f16)x0.x, (f16)x0.y, (f16)x0.z, (f16)x0.w};
        *reinterpret_cast<uint2*>(&u1h[0][tid * S1H]) = *reinterpret_cast<uint2*>(p);
    }
    __syncthreads();

    // ---- pipelined supersteps: waves0-3 do L1(t=s); waves4-7 do L2(t=s-1) ----
#pragma unroll 1
    for (int s = 0; s < SEQ + 2; ++s) {
        const int pr = s & 1, pn = pr ^ 1;
        if (!grpB) {
            // ---------- L1 gates(t=s) + lane-local cell update ----------
            const f16* u1r = u1h[pr];          // x(s), h1(s-1)
            f16* u1w = u1h[pn];                // h1(s) for next superstep
            f16* u2wA = u2h[pr];               // relu h1(s) for L2 next superstep
            const v8h B0 = *reinterpret_cast<const v8h*>(&u1r[mb * S1H + q * 8]);
            const v8h B1 = *reinterpret_cast<const v8h*>(&u1r[mb * S1H + 32 + q * 8]);
#pragma unroll
            for (int i = 0; i < 4; ++i) {
                const int tt = wa + 4 * i;
                if (tt < NT) {
                    v4f acc = {0.f, 0.f, 0.f, 0.f};
                    acc = __builtin_amdgcn_mfma_f32_16x16x32_f16(Af[i][0], B0, acc, 0, 0, 0);
                    acc = __builtin_amdgcn_mfma_f32_16x16x32_f16(Af[i][1], B1, acc, 0, 0, 0);
                    const float ig = sigf(acc[0] + br[i][0]);
                    const float fg = sigf(acc[1] + br[i][1]);
                    const float cg = tanhf_(acc[2] + br[i][2]);
                    const float og = sigf(acc[3] + br[i][3]);
                    cst[i] = fg * cst[i] + ig * cg;
                    const float h1 = og * tanhf_(cst[i]);
                    const int uc = tt * 4 + q;
                    if (uc < HID && mb < BB) {
                        u1w[mb * S1H + 4 + uc] = (f16)h1;
                        u2wA[mb * S2H + uc] = (f16)fmaxf(h1, 0.0f);
                    }
                }
            }
            // ---------- out store for t=s-2 (wave 3, 3 tiles) ----------
            if (wv == 3 && s >= 2) {
                float v = (lane < 32) ? fcw[pn][lane] : 0.0f;   // (s-1)&1 == pn
                v += __shfl_xor(v, 8);
                v += __shfl_xor(v, 16);
                if (lane < BB) out[(size_t)(s - 2) * BATCH + bbase + lane] = v + bfc;
            }
        } else {
            // ---------- x(s+1) prefetch (wave 4, 3 tiles) ----------
            float4 xr;
            if (wv == 4 && lane < BB) {
                const int tn = (s + 1 < SEQ) ? s + 1 : SEQ - 1;
                xr = *reinterpret_cast<const float4*>(
                    x + ((size_t)tn * BATCH + bbase + lane) * 4);
            }
            // ---------- L2 gates(t=s-1) + lane-local update + FC ----------
            const f16* u2r = u2h[pn];          // relu h1(s-1), h2(s-2)  ((s-1)&1 == pn)
            f16* u2wB = u2h[pr];               // h2(s-1)
            const v8h C0 = *reinterpret_cast<const v8h*>(&u2r[mb * S2H + q * 8]);
            const v8h C1 = *reinterpret_cast<const v8h*>(&u2r[mb * S2H + 32 + q * 8]);
            const v8h C2 = *reinterpret_cast<const v8h*>(&u2r[mb * S2H + 64 + q * 8]);
            const v8h C3 = *reinterpret_cast<const v8h*>(&u2r[mb * S2H + 96 + q * 8]);
            float fcp = 0.0f;
#pragma unroll
            for (int i = 0; i < 4; ++i) {
                const int tt = wa + 4 * i;
                if (tt < NT) {
                    v4f acc = {0.f, 0.f, 0.f, 0.f};
                    acc = __builtin_amdgcn_mfma_f32_16x16x32_f16(Af[i][0], C0, acc, 0, 0, 0);
                    acc = __builtin_amdgcn_mfma_f32_16x16x32_f16(Af[i][1], C1, acc, 0, 0, 0);
                    acc = __builtin_amdgcn_mfma_f32_16x16x32_f16(Af[i][2], C2, acc, 0, 0, 0);
                    acc = __builtin_amdgcn_mfma_f32_16x16x32_f16(Af[i][3], C3, acc, 0, 0, 0);
                    const float ig = sigf(acc[0] + br[i][0]);
                    const float fg = sigf(acc[1] + br[i][1]);
                    const float cg = tanhf_(acc[2] + br[i][2]);
                    const float og = sigf(acc[3] + br[i][3]);
                    const float cn = fg * cst[i] + ig * cg;
                    const float h2 = og * tanhf_(cn);
                    const int uc = tt * 4 + q;
                    if (s >= 1) {                      // t=s-1 valid
                        cst[i] = cn;
                        if (uc < HID) {
                            if (mb < BB) u2wB[mb * S2H + HID + uc] = (f16)h2;
                            fcp += fmaxf(h2, 0.0f) * wfr[i];
                        }
                    }
                }
            }
            fcp += __shfl_xor(fcp, 16);
            fcp += __shfl_xor(fcp, 32);
            if (s >= 1 && lane < BB) fcw[pr][wa * BB + lane] = fcp;
            if (wv == 4 && lane < BB) {   // x(s+1) into next-parity u1
                f16 p[4] = {(f16)xr.x, (f16)xr.y, (f16)xr.z, (f16)xr.w};
                *reinterpret_cast<uint2*>(&u1h[pn][lane * S1H]) = *reinterpret_cast<uint2*>(p);
            }
        }
        __syncthreads();   // the ONE barrier per superstep
    }
}

extern "C" void kernel_launch(void* const* d_in, const int* in_sizes, int n_in,
                              void* d_out, int out_size, void* d_ws, size_t ws_size,
                              hipStream_t stream) {
    const float* X    = (const float*)d_in[0];
    const float* Wih1 = (const float*)d_in[1];
    const float* Whh1 = (const float*)d_in[2];
    const float* Bih1 = (const float*)d_in[3];
    const float* Bhh1 = (const float*)d_in[4];
    const float* Wih2 = (const float*)d_in[5];
    const float* Whh2 = (const float*)d_in[6];
    const float* Bih2 = (const float*)d_in[7];
    const float* Bhh2 = (const float*)d_in[8];
    const float* Wfc  = (const float*)d_in[9];
    const float* Bfc  = (const float*)d_in[10];
    float* out = (float*)d_out;

    lstm2_fused<<<dim3(NBLK), dim3(NTHR), 0, stream>>>(
        X, Wih1, Whh1, Bih1, Bhh1, Wih2, Whh2, Bih2, Bhh2, Wfc, Bfc, out);
}

// Round 7
// 563.920 us; speedup vs baseline: 1.9265x; 1.1459x over previous
//
#include <hip/hip_runtime.h>
#include <cstdint>

#define SEQ 512
#define BATCH 2048
#define HID 50
#define BB 8              // real batches per block (N cols padded to 16)
#define NTHR 1024         // 16 waves: 0-7 = L1 group, 8-15 = L2 group
#define NBLK (BATCH / BB) // 256 blocks -> 1 per CU
#define NT 13             // gate-row tiles of 16 (200 -> 208, permuted rows)
#define S1H 72            // u1 row stride (halves): [x(4)|h1(50)|zero..64|pad..72]
#define S2H 136           // u2 row stride: [relu_h1(50)|h2(50)|zero..128|pad..136]

typedef _Float16 f16;
typedef _Float16 v8h __attribute__((ext_vector_type(8)));
typedef float    v4f __attribute__((ext_vector_type(4)));

__device__ __forceinline__ float sigf(float x) {
    return __builtin_amdgcn_rcpf(1.0f + __expf(-x));
}
__device__ __forceinline__ float tanhf_(float x) {
    return 1.0f - 2.0f * __builtin_amdgcn_rcpf(1.0f + __expf(2.0f * x));
}

// Row permutation (validated R5/R6): tile tt, in-tile row rho -> orig W row
// (rho%4)*50 + tt*4 + rho/4.  C layout (col=lane&15, row=(lane>>4)*4+reg)
// puts [i,f,g,o] of unit uc=tt*4+q, batch mb in one lane's 4 C-regs.

__global__ __launch_bounds__(NTHR, 1) void lstm2_fused(
    const float* __restrict__ x,
    const float* __restrict__ w_ih1, const float* __restrict__ w_hh1,
    const float* __restrict__ b_ih1, const float* __restrict__ b_hh1,
    const float* __restrict__ w_ih2, const float* __restrict__ w_hh2,
    const float* __restrict__ b_ih2, const float* __restrict__ b_hh2,
    const float* __restrict__ w_fc, const float* __restrict__ b_fc,
    float* __restrict__ out)
{
    __shared__ __align__(16) f16 u1h[2][16 * S1H];
    __shared__ __align__(16) f16 u2h[2][16 * S2H];
    __shared__ float fcw[2][64];

    const int tid  = threadIdx.x;
    const int wv   = tid >> 6;        // 0..15
    const int lane = tid & 63;
    const int mb   = lane & 15;       // A-row-in-tile | B col (batch)
    const int q    = lane >> 4;       // quad
    const int bbase = blockIdx.x * BB;

    const bool grpB = (wv >= 8);              // waves 8-15: L2
    const int  wa   = grpB ? (15 - wv) : wv;  // 0..7; mirrored so SIMD loads balance

    // ---- weight-stationary A fragments: wave owns tiles {wa, wa+8} ----
    v8h   Af[2][4];                   // [tile][ktile]; L1 uses kt 0..1, L2 kt 0..3
    float br[2][4], wfr[2], cst[2];
#pragma unroll
    for (int i = 0; i < 2; ++i) {
        const int tt = wa + 8 * i;
        const bool tv = (tt < NT);
        const int ru = tt * 4 + (mb >> 2);
        const bool rv = tv && (ru < HID);
        const int R = (mb & 3) * HID + ru;   // original gate-major W row
        if (!grpB) {
#pragma unroll
            for (int kt = 0; kt < 2; ++kt) {
                v8h f;
#pragma unroll
                for (int j = 0; j < 8; ++j) {
                    const int kk = kt * 32 + q * 8 + j;
                    float v = 0.0f;
                    if (rv) {
                        if (kk < 4) v = w_ih1[R * 4 + kk];
                        else if (kk < 54) v = w_hh1[R * HID + (kk - 4)];
                    }
                    f[j] = (f16)v;
                }
                Af[i][kt] = f;
            }
        } else {
#pragma unroll
            for (int kt = 0; kt < 4; ++kt) {
                v8h f;
#pragma unroll
                for (int j = 0; j < 8; ++j) {
                    const int kk = kt * 32 + q * 8 + j;
                    float v = 0.0f;
                    if (rv) {
                        if (kk < HID) v = w_ih2[R * HID + kk];
                        else if (kk < 2 * HID) v = w_hh2[R * HID + (kk - HID)];
                    }
                    f[j] = (f16)v;
                }
                Af[i][kt] = f;
            }
        }
        const int uc = tt * 4 + q;
        const bool cv = tv && (uc < HID);
#pragma unroll
        for (int g = 0; g < 4; ++g) {
            br[i][g] = cv ? (grpB ? (b_ih2[g * HID + uc] + b_hh2[g * HID + uc])
                                  : (b_ih1[g * HID + uc] + b_hh1[g * HID + uc]))
                          : 0.0f;
        }
        wfr[i] = (grpB && cv) ? w_fc[uc] : 0.0f;
        cst[i] = 0.0f;
    }
    const float bfc = b_fc[0];

    // ---- LDS init ----
    for (int idx = tid; idx < 2 * 16 * S1H; idx += NTHR) ((f16*)u1h)[idx] = (f16)0.0f;
    for (int idx = tid; idx < 2 * 16 * S2H; idx += NTHR) ((f16*)u2h)[idx] = (f16)0.0f;
    if (tid < 128) ((float*)fcw)[tid] = 0.0f;
    __syncthreads();
    if (tid < BB) {   // x(0) -> u1 parity 0
        const float4 x0 = *reinterpret_cast<const float4*>(x + (size_t)(bbase + tid) * 4);
        f16 p[4] = {(f16)x0.x, (f16)x0.y, (f16)x0.z, (f16)x0.w};
        *reinterpret_cast<uint2*>(&u1h[0][tid * S1H]) = *reinterpret_cast<uint2*>(p);
    }
    __syncthreads();

    // ---- pipelined supersteps: L1 group does t=s; L2 group does t=s-1 ----
#pragma unroll 1
    for (int s = 0; s < SEQ + 2; ++s) {
        const int pr = s & 1, pn = pr ^ 1;
        if (!grpB) {
            // ---------- L1 gates(t=s) + lane-local cell update ----------
            const f16* u1r = u1h[pr];          // x(s), h1(s-1)
            f16* u1w = u1h[pn];                // h1(s)
            f16* u2wA = u2h[pr];               // relu h1(s) for L2 next superstep
            const v8h B0 = *reinterpret_cast<const v8h*>(&u1r[mb * S1H + q * 8]);
            const v8h B1 = *reinterpret_cast<const v8h*>(&u1r[mb * S1H + 32 + q * 8]);
#pragma unroll
            for (int i = 0; i < 2; ++i) {
                const int tt = wa + 8 * i;
                if (tt < NT) {
                    v4f acc = {0.f, 0.f, 0.f, 0.f};
                    acc = __builtin_amdgcn_mfma_f32_16x16x32_f16(Af[i][0], B0, acc, 0, 0, 0);
                    acc = __builtin_amdgcn_mfma_f32_16x16x32_f16(Af[i][1], B1, acc, 0, 0, 0);
                    const float ig = sigf(acc[0] + br[i][0]);
                    const float fg = sigf(acc[1] + br[i][1]);
                    const float cg = tanhf_(acc[2] + br[i][2]);
                    const float og = sigf(acc[3] + br[i][3]);
                    cst[i] = fg * cst[i] + ig * cg;
                    const float h1 = og * tanhf_(cst[i]);
                    const int uc = tt * 4 + q;
                    if (uc < HID && mb < BB) {
                        u1w[mb * S1H + 4 + uc] = (f16)h1;
                        u2wA[mb * S2H + uc] = (f16)fmaxf(h1, 0.0f);
                    }
                }
            }
            // ---------- out store for t=s-2 (wave 3) ----------
            if (wv == 3 && s >= 2) {
                float v = fcw[pn][lane];            // lane = wa*8 + b
                v += __shfl_xor(v, 8);
                v += __shfl_xor(v, 16);
                v += __shfl_xor(v, 32);
                if (lane < BB) out[(size_t)(s - 2) * BATCH + bbase + lane] = v + bfc;
            }
        } else {
            // ---------- x(s+1) prefetch (wave 8: lightest L2 wave, wa=7) ----------
            float4 xr;
            if (wv == 8 && lane < BB) {
                const int tn = (s + 1 < SEQ) ? s + 1 : SEQ - 1;
                xr = *reinterpret_cast<const float4*>(
                    x + ((size_t)tn * BATCH + bbase + lane) * 4);
            }
            // ---------- L2 gates(t=s-1) + lane-local update + FC ----------
            const f16* u2r = u2h[pn];          // relu h1(s-1), h2(s-2)
            f16* u2wB = u2h[pr];               // h2(s-1)
            const v8h C0 = *reinterpret_cast<const v8h*>(&u2r[mb * S2H + q * 8]);
            const v8h C1 = *reinterpret_cast<const v8h*>(&u2r[mb * S2H + 32 + q * 8]);
            const v8h C2 = *reinterpret_cast<const v8h*>(&u2r[mb * S2H + 64 + q * 8]);
            const v8h C3 = *reinterpret_cast<const v8h*>(&u2r[mb * S2H + 96 + q * 8]);
            float fcp = 0.0f;
#pragma unroll
            for (int i = 0; i < 2; ++i) {
                const int tt = wa + 8 * i;
                if (tt < NT) {
                    v4f acc = {0.f, 0.f, 0.f, 0.f};
                    acc = __builtin_amdgcn_mfma_f32_16x16x32_f16(Af[i][0], C0, acc, 0, 0, 0);
                    acc = __builtin_amdgcn_mfma_f32_16x16x32_f16(Af[i][1], C1, acc, 0, 0, 0);
                    acc = __builtin_amdgcn_mfma_f32_16x16x32_f16(Af[i][2], C2, acc, 0, 0, 0);
                    acc = __builtin_amdgcn_mfma_f32_16x16x32_f16(Af[i][3], C3, acc, 0, 0, 0);
                    const float ig = sigf(acc[0] + br[i][0]);
                    const float fg = sigf(acc[1] + br[i][1]);
                    const float cg = tanhf_(acc[2] + br[i][2]);
                    const float og = sigf(acc[3] + br[i][3]);
                    const float cn = fg * cst[i] + ig * cg;
                    const float h2 = og * tanhf_(cn);
                    const int uc = tt * 4 + q;
                    if (s >= 1) {                      // t=s-1 valid
                        cst[i] = cn;
                        if (uc < HID) {
                            if (mb < BB) u2wB[mb * S2H + HID + uc] = (f16)h2;
                            fcp += fmaxf(h2, 0.0f) * wfr[i];
                        }
                    }
                }
            }
            fcp += __shfl_xor(fcp, 16);
            fcp += __shfl_xor(fcp, 32);
            if (s >= 1 && lane < BB) fcw[pr][wa * BB + lane] = fcp;
            if (wv == 8 && lane < BB) {   // x(s+1) into next-parity u1
                f16 p[4] = {(f16)xr.x, (f16)xr.y, (f16)xr.z, (f16)xr.w};
                *reinterpret_cast<uint2*>(&u1h[pn][lane * S1H]) = *reinterpret_cast<uint2*>(p);
            }
        }
        __syncthreads();   // the ONE barrier per superstep
    }
}

extern "C" void kernel_launch(void* const* d_in, const int* in_sizes, int n_in,
                              void* d_out, int out_size, void* d_ws, size_t ws_size,
                              hipStream_t stream) {
    const float* X    = (const float*)d_in[0];
    const float* Wih1 = (const float*)d_in[1];
    const float* Whh1 = (const float*)d_in[2];
    const float* Bih1 = (const float*)d_in[3];
    const float* Bhh1 = (const float*)d_in[4];
    const float* Wih2 = (const float*)d_in[5];
    const float* Whh2 = (const float*)d_in[6];
    const float* Bih2 = (const float*)d_in[7];
    const float* Bhh2 = (const float*)d_in[8];
    const float* Wfc  = (const float*)d_in[9];
    const float* Bfc  = (const float*)d_in[10];
    float* out = (float*)d_out;

    lstm2_fused<<<dim3(NBLK), dim3(NTHR), 0, stream>>>(
        X, Wih1, Whh1, Bih1, Bhh1, Wih2, Whh2, Bih2, Bhh2, Wfc, Bfc, out);
}

// Round 10
// 479.202 us; speedup vs baseline: 2.2671x; 1.1768x over previous
//
#include <hip/hip_runtime.h>
#include <cstdint>

#define SEQ 512
#define BATCH 2048
#define HID 50
#define BB 8              // real batches per block (N cols padded to 16)
#define NTHR 1024         // 16 waves: 0-7 = L1 group, 8-15 = L2 group
#define NBLK (BATCH / BB) // 256 blocks -> 1 per CU
#define NT 13             // gate-row tiles of 16 (200 -> 208, permuted rows)
#define S1H 72            // u1 row stride (halves): [x(4)|h1(50)|zero..64|pad..72]
#define S2H 136           // u2 row stride: [relu_h1(50)|h2(50)|zero..128|pad..136]

typedef _Float16 f16;
typedef _Float16 v8h __attribute__((ext_vector_type(8)));
typedef float    v4f __attribute__((ext_vector_type(4)));

// Row permutation (validated R5-R7): tile tt, in-tile row rho -> orig W row
// (rho%4)*50 + tt*4 + rho/4.  C layout (col=lane&15, row=(lane>>4)*4+reg)
// puts [i,f,g,o] of unit uc=tt*4+q, batch mb in one lane's 4 C-regs.
// R10 packing: lanes mb<8 handle tile wa (batch mb); lanes mb>=8 handle tile
// wa+8 (batch mb-8). Hi-tile accs move lanes via an IN-WAVE LDS BOUNCE
// (ds_write_b128 + ds_read_b128, per-wave private region, same-wave ordered)
// instead of __shfl_up — R8/R9 failed identically through the shfl path.

__global__ __launch_bounds__(NTHR, 1) void lstm2_fused(
    const float* __restrict__ x,
    const float* __restrict__ w_ih1, const float* __restrict__ w_hh1,
    const float* __restrict__ b_ih1, const float* __restrict__ b_hh1,
    const float* __restrict__ w_ih2, const float* __restrict__ w_hh2,
    const float* __restrict__ b_ih2, const float* __restrict__ b_hh2,
    const float* __restrict__ w_fc, const float* __restrict__ b_fc,
    float* __restrict__ out)
{
    __shared__ __align__(16) f16 u1h[2][16 * S1H];
    __shared__ __align__(16) f16 u2h[2][16 * S2H];
    __shared__ float fcw[2][64];
    __shared__ __align__(16) v4f bounce[16 * 64];   // per-wave 64-slot scratch

    const int tid  = threadIdx.x;
    const int wv   = tid >> 6;        // 0..15
    const int lane = tid & 63;
    const int mb   = lane & 15;       // A-row-in-tile | B col (batch)
    const int q    = lane >> 4;       // quad
    const int bbase = blockIdx.x * BB;

    const bool grpB = (wv >= 8);              // waves 8-15: L2
    const int  wa   = grpB ? (15 - wv) : wv;  // 0..7

    // ---- per-lane packed update identity ----
    const bool hiHalf = (mb >= 8);
    const int  myt    = hiHalf ? (wa + 8) : wa;
    const int  u_me   = myt * 4 + q;
    const bool valid_upd = (myt < NT) && (u_me < HID);
    const int  b_me   = mb & 7;
    const int  bslot  = (wv << 6) + lane;                    // own bounce slot
    const int  rslot  = (wv << 6) + (hiHalf ? lane - 8 : lane);

    // ---- weight-stationary A fragments: wave owns tiles {wa, wa+8} ----
    v8h Af[2][4];                     // [tile][ktile]; L1 uses kt 0..1, L2 kt 0..3
#pragma unroll
    for (int i = 0; i < 2; ++i) {
        const int tt = wa + 8 * i;
        const bool tv = (tt < NT);
        const int ru = tt * 4 + (mb >> 2);
        const bool rv = tv && (ru < HID);
        const int R = (mb & 3) * HID + ru;   // original gate-major W row
        if (!grpB) {
#pragma unroll
            for (int kt = 0; kt < 2; ++kt) {
                v8h f;
#pragma unroll
                for (int j = 0; j < 8; ++j) {
                    const int kk = kt * 32 + q * 8 + j;
                    float v = 0.0f;
                    if (rv) {
                        if (kk < 4) v = w_ih1[R * 4 + kk];
                        else if (kk < 54) v = w_hh1[R * HID + (kk - 4)];
                    }
                    f[j] = (f16)v;
                }
                Af[i][kt] = f;
            }
        } else {
#pragma unroll
            for (int kt = 0; kt < 4; ++kt) {
                v8h f;
#pragma unroll
                for (int j = 0; j < 8; ++j) {
                    const int kk = kt * 32 + q * 8 + j;
                    float v = 0.0f;
                    if (rv) {
                        if (kk < HID) v = w_ih2[R * HID + kk];
                        else if (kk < 2 * HID) v = w_hh2[R * HID + (kk - HID)];
                    }
                    f[j] = (f16)v;
                }
                Af[i][kt] = f;
            }
        }
    }
    // per-lane biases / fc weight for the packed identity
    float br0 = 0.f, br1 = 0.f, br2 = 0.f, br3 = 0.f, wfc_me = 0.f;
    if (valid_upd) {
        if (!grpB) {
            br0 = b_ih1[0 * HID + u_me] + b_hh1[0 * HID + u_me];
            br1 = b_ih1[1 * HID + u_me] + b_hh1[1 * HID + u_me];
            br2 = b_ih1[2 * HID + u_me] + b_hh1[2 * HID + u_me];
            br3 = b_ih1[3 * HID + u_me] + b_hh1[3 * HID + u_me];
        } else {
            br0 = b_ih2[0 * HID + u_me] + b_hh2[0 * HID + u_me];
            br1 = b_ih2[1 * HID + u_me] + b_hh2[1 * HID + u_me];
            br2 = b_ih2[2 * HID + u_me] + b_hh2[2 * HID + u_me];
            br3 = b_ih2[3 * HID + u_me] + b_hh2[3 * HID + u_me];
            wfc_me = w_fc[u_me];
        }
    }
    const float bfc = b_fc[0];
    float c_me = 0.0f;

    // ---- LDS init ----
    for (int idx = tid; idx < 2 * 16 * S1H; idx += NTHR) ((f16*)u1h)[idx] = (f16)0.0f;
    for (int idx = tid; idx < 2 * 16 * S2H; idx += NTHR) ((f16*)u2h)[idx] = (f16)0.0f;
    if (tid < 128) ((float*)fcw)[tid] = 0.0f;
    __syncthreads();
    if (tid < BB) {   // x(0) -> u1 parity 0
        const float4 x0 = *reinterpret_cast<const float4*>(x + (size_t)(bbase + tid) * 4);
        f16 p[4] = {(f16)x0.x, (f16)x0.y, (f16)x0.z, (f16)x0.w};
        *reinterpret_cast<uint2*>(&u1h[0][tid * S1H]) = *reinterpret_cast<uint2*>(p);
    }
    __syncthreads();

    // ---- pipelined supersteps: L1 group does t=s; L2 group does t=s-1 ----
#pragma unroll 1
    for (int s = 0; s < SEQ + 2; ++s) {
        const int pr = s & 1, pn = pr ^ 1;
        if (!grpB) {
            // ---------- L1 gates(t=s), packed lane-local update ----------
            const f16* u1r = u1h[pr];          // x(s), h1(s-1)
            f16* u1w = u1h[pn];                // h1(s)
            f16* u2wA = u2h[pr];               // relu h1(s) for L2 next superstep
            const v8h B0 = *reinterpret_cast<const v8h*>(&u1r[mb * S1H + q * 8]);
            const v8h B1 = *reinterpret_cast<const v8h*>(&u1r[mb * S1H + 32 + q * 8]);
            v4f a0 = {0.f, 0.f, 0.f, 0.f}, a1 = {0.f, 0.f, 0.f, 0.f};
            a0 = __builtin_amdgcn_mfma_f32_16x16x32_f16(Af[0][0], B0, a0, 0, 0, 0);
            a0 = __builtin_amdgcn_mfma_f32_16x16x32_f16(Af[0][1], B1, a0, 0, 0, 0);
            if (wa < NT - 8) {
                a1 = __builtin_amdgcn_mfma_f32_16x16x32_f16(Af[1][0], B0, a1, 0, 0, 0);
                a1 = __builtin_amdgcn_mfma_f32_16x16x32_f16(Af[1][1], B1, a1, 0, 0, 0);
            }
            // in-wave LDS bounce: all lanes write a1, hi lanes read lane-8's
            bounce[bslot] = a1;
            const v4f av = bounce[rslot];
            const float m0 = hiHalf ? av[0] : a0[0];
            const float m1 = hiHalf ? av[1] : a0[1];
            const float m2 = hiHalf ? av[2] : a0[2];
            const float m3 = hiHalf ? av[3] : a0[3];
            // fused cell update (8 trans; exonerated by R8==R9)
            const float A  = 1.0f + __expf(-(m0 + br0));
            const float F  = 1.0f + __expf(-(m1 + br1));
            const float Bv = 1.0f + __expf(2.0f * (m2 + br2));
            const float C  = 1.0f + __expf(-(m3 + br3));
            c_me = __builtin_amdgcn_rcpf(F) * c_me
                 + (Bv - 2.0f) * __builtin_amdgcn_rcpf(A * Bv);
            const float D = 1.0f + __expf(2.0f * c_me);
            const float h1v = (D - 2.0f) * __builtin_amdgcn_rcpf(C * D);
            if (valid_upd) {
                u1w[b_me * S1H + 4 + u_me] = (f16)h1v;
                u2wA[b_me * S2H + u_me] = (f16)fmaxf(h1v, 0.0f);
            }
            // ---------- out store for t=s-2 (wave 3) ----------
            if (wv == 3 && s >= 2) {
                float v = fcw[pn][lane];            // lane = wa*8 + b
                v += __shfl_xor(v, 8);
                v += __shfl_xor(v, 16);
                v += __shfl_xor(v, 32);
                if (lane < BB) out[(size_t)(s - 2) * BATCH + bbase + lane] = v + bfc;
            }
        } else {
            // ---------- x(s+1) prefetch (wave 8) ----------
            float4 xr;
            if (wv == 8 && lane < BB) {
                const int tn = (s + 1 < SEQ) ? s + 1 : SEQ - 1;
                xr = *reinterpret_cast<const float4*>(
                    x + ((size_t)tn * BATCH + bbase + lane) * 4);
            }
            // ---------- L2 gates(t=s-1), packed lane-local update + FC ----------
            const f16* u2r = u2h[pn];          // relu h1(s-1), h2(s-2)
            f16* u2wB = u2h[pr];               // h2(s-1)
            const v8h C0 = *reinterpret_cast<const v8h*>(&u2r[mb * S2H + q * 8]);
            const v8h C1 = *reinterpret_cast<const v8h*>(&u2r[mb * S2H + 32 + q * 8]);
            const v8h C2 = *reinterpret_cast<const v8h*>(&u2r[mb * S2H + 64 + q * 8]);
            const v8h C3 = *reinterpret_cast<const v8h*>(&u2r[mb * S2H + 96 + q * 8]);
            v4f a0 = {0.f, 0.f, 0.f, 0.f}, a1 = {0.f, 0.f, 0.f, 0.f};
            a0 = __builtin_amdgcn_mfma_f32_16x16x32_f16(Af[0][0], C0, a0, 0, 0, 0);
            a0 = __builtin_amdgcn_mfma_f32_16x16x32_f16(Af[0][1], C1, a0, 0, 0, 0);
            a0 = __builtin_amdgcn_mfma_f32_16x16x32_f16(Af[0][2], C2, a0, 0, 0, 0);
            a0 = __builtin_amdgcn_mfma_f32_16x16x32_f16(Af[0][3], C3, a0, 0, 0, 0);
            if (wa < NT - 8) {
                a1 = __builtin_amdgcn_mfma_f32_16x16x32_f16(Af[1][0], C0, a1, 0, 0, 0);
                a1 = __builtin_amdgcn_mfma_f32_16x16x32_f16(Af[1][1], C1, a1, 0, 0, 0);
                a1 = __builtin_amdgcn_mfma_f32_16x16x32_f16(Af[1][2], C2, a1, 0, 0, 0);
                a1 = __builtin_amdgcn_mfma_f32_16x16x32_f16(Af[1][3], C3, a1, 0, 0, 0);
            }
            bounce[bslot] = a1;
            const v4f av = bounce[rslot];
            const float m0 = hiHalf ? av[0] : a0[0];
            const float m1 = hiHalf ? av[1] : a0[1];
            const float m2 = hiHalf ? av[2] : a0[2];
            const float m3 = hiHalf ? av[3] : a0[3];
            const float A  = 1.0f + __expf(-(m0 + br0));
            const float F  = 1.0f + __expf(-(m1 + br1));
            const float Bv = 1.0f + __expf(2.0f * (m2 + br2));
            const float C  = 1.0f + __expf(-(m3 + br3));
            const float cn = __builtin_amdgcn_rcpf(F) * c_me
                           + (Bv - 2.0f) * __builtin_amdgcn_rcpf(A * Bv);
            const float D = 1.0f + __expf(2.0f * cn);
            const float h2v = (D - 2.0f) * __builtin_amdgcn_rcpf(C * D);
            float p = 0.0f;
            if (s >= 1) {                       // t=s-1 valid
                c_me = cn;
                if (valid_upd) u2wB[b_me * S2H + HID + u_me] = (f16)h2v;
                p = fmaxf(h2v, 0.0f) * wfc_me;  // wfc_me=0 on invalid lanes
            }
            p += __shfl_xor(p, 8);              // merge tile pair (same batch)
            p += __shfl_xor(p, 16);             // merge quads
            p += __shfl_xor(p, 32);
            if (s >= 1 && lane < BB) fcw[pr][wa * BB + lane] = p;
            if (wv == 8 && lane < BB) {   // x(s+1) into next-parity u1
                f16 pk[4] = {(f16)xr.x, (f16)xr.y, (f16)xr.z, (f16)xr.w};
                *reinterpret_cast<uint2*>(&u1h[pn][lane * S1H]) = *reinterpret_cast<uint2*>(pk);
            }
        }
        __syncthreads();   // the ONE barrier per superstep
    }
}

extern "C" void kernel_launch(void* const* d_in, const int* in_sizes, int n_in,
                              void* d_out, int out_size, void* d_ws, size_t ws_size,
                              hipStream_t stream) {
    const float* X    = (const float*)d_in[0];
    const float* Wih1 = (const float*)d_in[1];
    const float* Whh1 = (const float*)d_in[2];
    const float* Bih1 = (const float*)d_in[3];
    const float* Bhh1 = (const float*)d_in[4];
    const float* Wih2 = (const float*)d_in[5];
    const float* Whh2 = (const float*)d_in[6];
    const float* Bih2 = (const float*)d_in[7];
    const float* Bhh2 = (const float*)d_in[8];
    const float* Wfc  = (const float*)d_in[9];
    const float* Bfc  = (const float*)d_in[10];
    float* out = (float*)d_out;

    lstm2_fused<<<dim3(NBLK), dim3(NTHR), 0, stream>>>(
        X, Wih1, Whh1, Bih1, Bhh1, Wih2, Whh2, Bih2, Bhh2, Wfc, Bfc, out);
}

// Round 11
// 431.874 us; speedup vs baseline: 2.5155x; 1.1096x over previous
//
#include <hip/hip_runtime.h>
#include <cstdint>

#define SEQ 512
#define BATCH 2048
#define HID 50
#define BB 8              // real batches per block
#define NTHR 1024         // 16 waves: 0-7 = L1 group, 8-15 = L2 group
#define NBLK (BATCH / BB) // 256 blocks -> 1 per CU
#define NT 13             // gate-row tiles of 16 (200 -> 208, permuted rows)
#define S1H 72            // u1 row stride (halves): [x(4)|h1(50)|zero..64|pad..72]
#define S2H 136           // u2 row stride: [relu_h1(50)|h2(50)|zero..128|pad..136]

typedef _Float16 f16;
typedef _Float16 v8h __attribute__((ext_vector_type(8)));
typedef float    v4f __attribute__((ext_vector_type(4)));

// Row permutation (validated R5-R10): tile tt, in-tile row rho -> orig W row
// (rho%4)*50 + tt*4 + rho/4.  C layout (col=lane&15, row=(lane>>4)*4+reg)
// puts [i,f,g,o] of unit uc=tt*4+q, batch col in one lane's 4 C-regs.
// R11: B columns carry batch (n&7) — lanes mb<8 take lo-tile gates from a0,
// lanes mb>=8 take hi-tile gates from their own a1 (no bounce, no shuffle).

__global__ __launch_bounds__(NTHR, 1) void lstm2_fused(
    const float* __restrict__ x,
    const float* __restrict__ w_ih1, const float* __restrict__ w_hh1,
    const float* __restrict__ b_ih1, const float* __restrict__ b_hh1,
    const float* __restrict__ w_ih2, const float* __restrict__ w_hh2,
    const float* __restrict__ b_ih2, const float* __restrict__ b_hh2,
    const float* __restrict__ w_fc, const float* __restrict__ b_fc,
    float* __restrict__ out)
{
    __shared__ __align__(16) f16 u1h[2][BB * S1H];
    __shared__ __align__(16) f16 u2h[2][BB * S2H];
    __shared__ float fcw[2][64];

    const int tid  = threadIdx.x;
    const int wv   = tid >> 6;        // 0..15
    const int lane = tid & 63;
    const int mb   = lane & 15;       // A-row-in-tile | C col
    const int q    = lane >> 4;       // quad
    const int bbase = blockIdx.x * BB;

    const bool grpB = (wv >= 8);              // waves 8-15: L2
    const int  wa   = grpB ? (15 - wv) : wv;  // 0..7

    // ---- per-lane packed update identity ----
    const bool hiHalf = (mb >= 8);
    const int  myt    = hiHalf ? (wa + 8) : wa;
    const int  u_me   = myt * 4 + q;
    const bool valid_upd = (myt < NT) && (u_me < HID);
    const int  b_me   = mb & 7;       // batch: B-load row AND update identity

    // ---- weight-stationary A fragments: wave owns tiles {wa, wa+8} ----
    v8h Af[2][4];                     // [tile][ktile]; L1 uses kt 0..1, L2 kt 0..3
#pragma unroll
    for (int i = 0; i < 2; ++i) {
        const int tt = wa + 8 * i;
        const bool tv = (tt < NT);
        const int ru = tt * 4 + (mb >> 2);
        const bool rv = tv && (ru < HID);
        const int R = (mb & 3) * HID + ru;   // original gate-major W row
        if (!grpB) {
#pragma unroll
            for (int kt = 0; kt < 2; ++kt) {
                v8h f;
#pragma unroll
                for (int j = 0; j < 8; ++j) {
                    const int kk = kt * 32 + q * 8 + j;
                    float v = 0.0f;
                    if (rv) {
                        if (kk < 4) v = w_ih1[R * 4 + kk];
                        else if (kk < 54) v = w_hh1[R * HID + (kk - 4)];
                    }
                    f[j] = (f16)v;
                }
                Af[i][kt] = f;
            }
        } else {
#pragma unroll
            for (int kt = 0; kt < 4; ++kt) {
                v8h f;
#pragma unroll
                for (int j = 0; j < 8; ++j) {
                    const int kk = kt * 32 + q * 8 + j;
                    float v = 0.0f;
                    if (rv) {
                        if (kk < HID) v = w_ih2[R * HID + kk];
                        else if (kk < 2 * HID) v = w_hh2[R * HID + (kk - HID)];
                    }
                    f[j] = (f16)v;
                }
                Af[i][kt] = f;
            }
        }
    }
    // per-lane biases / fc weight for the packed identity
    float br0 = 0.f, br1 = 0.f, br2 = 0.f, br3 = 0.f, wfc_me = 0.f;
    if (valid_upd) {
        if (!grpB) {
            br0 = b_ih1[0 * HID + u_me] + b_hh1[0 * HID + u_me];
            br1 = b_ih1[1 * HID + u_me] + b_hh1[1 * HID + u_me];
            br2 = b_ih1[2 * HID + u_me] + b_hh1[2 * HID + u_me];
            br3 = b_ih1[3 * HID + u_me] + b_hh1[3 * HID + u_me];
        } else {
            br0 = b_ih2[0 * HID + u_me] + b_hh2[0 * HID + u_me];
            br1 = b_ih2[1 * HID + u_me] + b_hh2[1 * HID + u_me];
            br2 = b_ih2[2 * HID + u_me] + b_hh2[2 * HID + u_me];
            br3 = b_ih2[3 * HID + u_me] + b_hh2[3 * HID + u_me];
            wfc_me = w_fc[u_me];
        }
    }
    const float bfc = b_fc[0];
    float c_me = 0.0f;

    // ---- LDS init ----
    for (int idx = tid; idx < 2 * BB * S1H; idx += NTHR) ((f16*)u1h)[idx] = (f16)0.0f;
    for (int idx = tid; idx < 2 * BB * S2H; idx += NTHR) ((f16*)u2h)[idx] = (f16)0.0f;
    if (tid < 128) ((float*)fcw)[tid] = 0.0f;
    __syncthreads();
    if (tid < BB) {   // x(0) -> u1 parity 0
        const float4 x0 = *reinterpret_cast<const float4*>(x + (size_t)(bbase + tid) * 4);
        f16 p[4] = {(f16)x0.x, (f16)x0.y, (f16)x0.z, (f16)x0.w};
        *reinterpret_cast<uint2*>(&u1h[0][tid * S1H]) = *reinterpret_cast<uint2*>(p);
    }
    __syncthreads();

    // ---- pipelined supersteps: L1 group does t=s; L2 group does t=s-1 ----
#pragma unroll 1
    for (int s = 0; s < SEQ + 2; ++s) {
        const int pr = s & 1, pn = pr ^ 1;
        if (!grpB) {
            // ---------- L1 gates(t=s), packed lane-local update ----------
            const f16* u1r = u1h[pr];          // x(s), h1(s-1)
            f16* u1w = u1h[pn];                // h1(s)
            f16* u2wA = u2h[pr];               // relu h1(s) for L2 next superstep
            // B columns: batch b_me in col mb AND col mb^8 (broadcast read)
            const v8h B0 = *reinterpret_cast<const v8h*>(&u1r[b_me * S1H + q * 8]);
            const v8h B1 = *reinterpret_cast<const v8h*>(&u1r[b_me * S1H + 32 + q * 8]);
            v4f a0 = {0.f, 0.f, 0.f, 0.f}, a1 = {0.f, 0.f, 0.f, 0.f};
            a0 = __builtin_amdgcn_mfma_f32_16x16x32_f16(Af[0][0], B0, a0, 0, 0, 0);
            a0 = __builtin_amdgcn_mfma_f32_16x16x32_f16(Af[0][1], B1, a0, 0, 0, 0);
            if (wa < NT - 8) {
                a1 = __builtin_amdgcn_mfma_f32_16x16x32_f16(Af[1][0], B0, a1, 0, 0, 0);
                a1 = __builtin_amdgcn_mfma_f32_16x16x32_f16(Af[1][1], B1, a1, 0, 0, 0);
            }
            // per-lane tile select: own registers, no data movement
            const float m0 = hiHalf ? a1[0] : a0[0];
            const float m1 = hiHalf ? a1[1] : a0[1];
            const float m2 = hiHalf ? a1[2] : a0[2];
            const float m3 = hiHalf ? a1[3] : a0[3];
            // fused cell update (8 trans; validated R10)
            const float A  = 1.0f + __expf(-(m0 + br0));
            const float F  = 1.0f + __expf(-(m1 + br1));
            const float Bv = 1.0f + __expf(2.0f * (m2 + br2));
            const float C  = 1.0f + __expf(-(m3 + br3));
            c_me = __builtin_amdgcn_rcpf(F) * c_me
                 + (Bv - 2.0f) * __builtin_amdgcn_rcpf(A * Bv);
            const float D = 1.0f + __expf(2.0f * c_me);
            const float h1v = (D - 2.0f) * __builtin_amdgcn_rcpf(C * D);
            if (valid_upd) {
                u1w[b_me * S1H + 4 + u_me] = (f16)h1v;
                u2wA[b_me * S2H + u_me] = (f16)fmaxf(h1v, 0.0f);
            }
            // ---------- out store for t=s-2 (wave 3) ----------
            if (wv == 3 && s >= 2) {
                float v = fcw[pn][lane];            // lane = wa*8 + b
                v += __shfl_xor(v, 8);
                v += __shfl_xor(v, 16);
                v += __shfl_xor(v, 32);
                if (lane < BB) out[(size_t)(s - 2) * BATCH + bbase + lane] = v + bfc;
            }
        } else {
            // ---------- x(s+1) prefetch (wave 8) ----------
            float4 xr;
            if (wv == 8 && lane < BB) {
                const int tn = (s + 1 < SEQ) ? s + 1 : SEQ - 1;
                xr = *reinterpret_cast<const float4*>(
                    x + ((size_t)tn * BATCH + bbase + lane) * 4);
            }
            // ---------- L2 gates(t=s-1), packed lane-local update + FC ----------
            const f16* u2r = u2h[pn];          // relu h1(s-1), h2(s-2)
            f16* u2wB = u2h[pr];               // h2(s-1)
            const v8h C0 = *reinterpret_cast<const v8h*>(&u2r[b_me * S2H + q * 8]);
            const v8h C1 = *reinterpret_cast<const v8h*>(&u2r[b_me * S2H + 32 + q * 8]);
            const v8h C2 = *reinterpret_cast<const v8h*>(&u2r[b_me * S2H + 64 + q * 8]);
            const v8h C3 = *reinterpret_cast<const v8h*>(&u2r[b_me * S2H + 96 + q * 8]);
            v4f a0 = {0.f, 0.f, 0.f, 0.f}, a1 = {0.f, 0.f, 0.f, 0.f};
            a0 = __builtin_amdgcn_mfma_f32_16x16x32_f16(Af[0][0], C0, a0, 0, 0, 0);
            a0 = __builtin_amdgcn_mfma_f32_16x16x32_f16(Af[0][1], C1, a0, 0, 0, 0);
            a0 = __builtin_amdgcn_mfma_f32_16x16x32_f16(Af[0][2], C2, a0, 0, 0, 0);
            a0 = __builtin_amdgcn_mfma_f32_16x16x32_f16(Af[0][3], C3, a0, 0, 0, 0);
            if (wa < NT - 8) {
                a1 = __builtin_amdgcn_mfma_f32_16x16x32_f16(Af[1][0], C0, a1, 0, 0, 0);
                a1 = __builtin_amdgcn_mfma_f32_16x16x32_f16(Af[1][1], C1, a1, 0, 0, 0);
                a1 = __builtin_amdgcn_mfma_f32_16x16x32_f16(Af[1][2], C2, a1, 0, 0, 0);
                a1 = __builtin_amdgcn_mfma_f32_16x16x32_f16(Af[1][3], C3, a1, 0, 0, 0);
            }
            const float m0 = hiHalf ? a1[0] : a0[0];
            const float m1 = hiHalf ? a1[1] : a0[1];
            const float m2 = hiHalf ? a1[2] : a0[2];
            const float m3 = hiHalf ? a1[3] : a0[3];
            const float A  = 1.0f + __expf(-(m0 + br0));
            const float F  = 1.0f + __expf(-(m1 + br1));
            const float Bv = 1.0f + __expf(2.0f * (m2 + br2));
            const float C  = 1.0f + __expf(-(m3 + br3));
            const float cn = __builtin_amdgcn_rcpf(F) * c_me
                           + (Bv - 2.0f) * __builtin_amdgcn_rcpf(A * Bv);
            const float D = 1.0f + __expf(2.0f * cn);
            const float h2v = (D - 2.0f) * __builtin_amdgcn_rcpf(C * D);
            float p = 0.0f;
            if (s >= 1) {                       // t=s-1 valid
                c_me = cn;
                if (valid_upd) u2wB[b_me * S2H + HID + u_me] = (f16)h2v;
                p = fmaxf(h2v, 0.0f) * wfc_me;  // wfc_me=0 on invalid lanes
            }
            p += __shfl_xor(p, 8);              // merge tile pair (same batch)
            p += __shfl_xor(p, 16);             // merge quads
            p += __shfl_xor(p, 32);
            if (s >= 1 && lane < BB) fcw[pr][wa * BB + lane] = p;
            if (wv == 8 && lane < BB) {   // x(s+1) into next-parity u1
                f16 pk[4] = {(f16)xr.x, (f16)xr.y, (f16)xr.z, (f16)xr.w};
                *reinterpret_cast<uint2*>(&u1h[pn][lane * S1H]) = *reinterpret_cast<uint2*>(pk);
            }
        }
        __syncthreads();   // the ONE barrier per superstep
    }
}

extern "C" void kernel_launch(void* const* d_in, const int* in_sizes, int n_in,
                              void* d_out, int out_size, void* d_ws, size_t ws_size,
                              hipStream_t stream) {
    const float* X    = (const float*)d_in[0];
    const float* Wih1 = (const float*)d_in[1];
    const float* Whh1 = (const float*)d_in[2];
    const float* Bih1 = (const float*)d_in[3];
    const float* Bhh1 = (const float*)d_in[4];
    const float* Wih2 = (const float*)d_in[5];
    const float* Whh2 = (const float*)d_in[6];
    const float* Bih2 = (const float*)d_in[7];
    const float* Bhh2 = (const float*)d_in[8];
    const float* Wfc  = (const float*)d_in[9];
    const float* Bfc  = (const float*)d_in[10];
    float* out = (float*)d_out;

    lstm2_fused<<<dim3(NBLK), dim3(NTHR), 0, stream>>>(
        X, Wih1, Whh1, Bih1, Bhh1, Wih2, Whh2, Bih2, Bhh2, Wfc, Bfc, out);
}

// Round 12
// 420.408 us; speedup vs baseline: 2.5841x; 1.0273x over previous
//
#include <hip/hip_runtime.h>
#include <cstdint>

#define SEQ 512
#define BATCH 2048
#define HID 50
#define BB 8              // real batches per block
#define NTHR 1024         // 16 waves: 0-7 = L1 group, 8-15 = L2 group
#define NBLK (BATCH / BB) // 256 blocks -> 1 per CU
#define NT 13             // gate-row tiles of 16 (200 -> 208, permuted rows)
#define S1H 72            // u1 stride (halves): [x(4)|h1(50)|ONE@54|zero..64|pad..72]
#define S2H 136           // u2 stride: [relu_h1(50)|h2(50)|ONE@100|zero..128|pad..136]

typedef _Float16 f16;
typedef _Float16 v8h __attribute__((ext_vector_type(8)));
typedef float    v4f __attribute__((ext_vector_type(4)));

#if __has_builtin(__builtin_amdgcn_exp2f)
#define EXP2F(x) __builtin_amdgcn_exp2f(x)
#else
#define EXP2F(x) exp2f(x)
#endif
#define RCPF(x) __builtin_amdgcn_rcpf(x)
#define LOG2E 1.44269504f

// Row permutation (validated R5-R11): tile tt, in-tile row rho -> orig W row
// (rho%4)*50 + tt*4 + rho/4.  C layout (col=lane&15, row=(lane>>4)*4+reg)
// puts [i,f,g,o] of unit uc=tt*4+q, batch col&7 in one lane's 4 C-regs.
// R11 packing: B cols carry batch n&7; lanes mb<8 use a0, mb>=8 use own a1.
// R12: biases ride a constant-1.0 u-column (k=54 / k=100); gate rows are
// pre-scaled (i,f,o: -log2e; g: +2log2e) so the update uses raw v_exp_f32.

__global__ __launch_bounds__(NTHR, 1) void lstm2_fused(
    const float* __restrict__ x,
    const float* __restrict__ w_ih1, const float* __restrict__ w_hh1,
    const float* __restrict__ b_ih1, const float* __restrict__ b_hh1,
    const float* __restrict__ w_ih2, const float* __restrict__ w_hh2,
    const float* __restrict__ b_ih2, const float* __restrict__ b_hh2,
    const float* __restrict__ w_fc, const float* __restrict__ b_fc,
    float* __restrict__ out)
{
    __shared__ __align__(16) f16 u1h[2][BB * S1H];
    __shared__ __align__(16) f16 u2h[2][BB * S2H];
    __shared__ float fcw[2][64];

    const int tid  = threadIdx.x;
    const int wv   = tid >> 6;        // 0..15
    const int lane = tid & 63;
    const int mb   = lane & 15;       // A-row-in-tile | C col
    const int q    = lane >> 4;       // quad
    const int bbase = blockIdx.x * BB;

    const bool grpB = (wv >= 8);              // waves 8-15: L2
    const int  wa   = grpB ? (15 - wv) : wv;  // 0..7

    // ---- per-lane packed update identity ----
    const bool hiHalf = (mb >= 8);
    const int  myt    = hiHalf ? (wa + 8) : wa;
    const int  u_me   = myt * 4 + q;
    const bool valid_upd = (myt < NT) && (u_me < HID);
    const int  b_me   = mb & 7;       // batch: B-load row AND update identity

    // gate scale for this lane's A-fragment rows (gate = mb&3)
    const int   gidx = mb & 3;
    const float sc   = (gidx == 2) ? (2.0f * LOG2E) : (-LOG2E);

    // ---- weight-stationary A fragments (scaled, bias column) ----
    v8h Af[2][4];                     // [tile][ktile]; L1 uses kt 0..1, L2 kt 0..3
#pragma unroll
    for (int i = 0; i < 2; ++i) {
        const int tt = wa + 8 * i;
        const bool tv = (tt < NT);
        const int ru = tt * 4 + (mb >> 2);
        const bool rv = tv && (ru < HID);
        const int R = gidx * HID + ru;       // original gate-major W row
        if (!grpB) {
#pragma unroll
            for (int kt = 0; kt < 2; ++kt) {
                v8h f;
#pragma unroll
                for (int j = 0; j < 8; ++j) {
                    const int kk = kt * 32 + q * 8 + j;
                    float v = 0.0f;
                    if (rv) {
                        if (kk < 4) v = w_ih1[R * 4 + kk];
                        else if (kk < 54) v = w_hh1[R * HID + (kk - 4)];
                        else if (kk == 54) v = b_ih1[R] + b_hh1[R];
                    }
                    f[j] = (f16)(v * sc);
                }
                Af[i][kt] = f;
            }
        } else {
#pragma unroll
            for (int kt = 0; kt < 4; ++kt) {
                v8h f;
#pragma unroll
                for (int j = 0; j < 8; ++j) {
                    const int kk = kt * 32 + q * 8 + j;
                    float v = 0.0f;
                    if (rv) {
                        if (kk < HID) v = w_ih2[R * HID + kk];
                        else if (kk < 2 * HID) v = w_hh2[R * HID + (kk - HID)];
                        else if (kk == 100) v = b_ih2[R] + b_hh2[R];
                    }
                    f[j] = (f16)(v * sc);
                }
                Af[i][kt] = f;
            }
        }
    }
    const float wfc_me = (grpB && valid_upd) ? w_fc[u_me] : 0.0f;
    const float bfc = b_fc[0];
    float c_me = 0.0f;

    // ---- LDS init ----
    for (int idx = tid; idx < 2 * BB * S1H; idx += NTHR) ((f16*)u1h)[idx] = (f16)0.0f;
    for (int idx = tid; idx < 2 * BB * S2H; idx += NTHR) ((f16*)u2h)[idx] = (f16)0.0f;
    if (tid < 128) ((float*)fcw)[tid] = 0.0f;
    __syncthreads();
    if (tid < BB) {   // x(0) -> u1 parity 0
        const float4 x0 = *reinterpret_cast<const float4*>(x + (size_t)(bbase + tid) * 4);
        f16 p[4] = {(f16)x0.x, (f16)x0.y, (f16)x0.z, (f16)x0.w};
        *reinterpret_cast<uint2*>(&u1h[0][tid * S1H]) = *reinterpret_cast<uint2*>(p);
    }
    if (tid < 16) {   // constant-1 bias columns, both parities
        const int p = tid >> 3, b = tid & 7;
        u1h[p][b * S1H + 54] = (f16)1.0f;
        u2h[p][b * S2H + 100] = (f16)1.0f;
    }
    __syncthreads();

    // ---- hoisted per-parity LDS pointers ----
    const f16* u1rp[2] = {u1h[0] + b_me * S1H, u1h[1] + b_me * S1H};
    const f16* u2rp[2] = {u2h[0] + b_me * S2H, u2h[1] + b_me * S2H};
    f16* u1wp[2] = {u1h[0] + b_me * S1H, u1h[1] + b_me * S1H};
    f16* u2wp[2] = {u2h[0] + b_me * S2H, u2h[1] + b_me * S2H};

    // ---- superstep body (pr/pn become literals in the 2x-unrolled loop) ----
    auto body = [&](int s, int pr, int pn) __attribute__((always_inline)) {
        if (!grpB) {
            // ---------- L1 gates(t=s), packed lane-local update ----------
            const f16* u1r = u1rp[pr];
            const v8h B0 = *reinterpret_cast<const v8h*>(&u1r[q * 8]);
            const v8h B1 = *reinterpret_cast<const v8h*>(&u1r[32 + q * 8]);
            v4f a0 = {0.f, 0.f, 0.f, 0.f}, a1 = {0.f, 0.f, 0.f, 0.f};
            a0 = __builtin_amdgcn_mfma_f32_16x16x32_f16(Af[0][0], B0, a0, 0, 0, 0);
            a0 = __builtin_amdgcn_mfma_f32_16x16x32_f16(Af[0][1], B1, a0, 0, 0, 0);
            if (wa < NT - 8) {
                a1 = __builtin_amdgcn_mfma_f32_16x16x32_f16(Af[1][0], B0, a1, 0, 0, 0);
                a1 = __builtin_amdgcn_mfma_f32_16x16x32_f16(Af[1][1], B1, a1, 0, 0, 0);
            }
            const float m0 = hiHalf ? a1[0] : a0[0];
            const float m1 = hiHalf ? a1[1] : a0[1];
            const float m2 = hiHalf ? a1[2] : a0[2];
            const float m3 = hiHalf ? a1[3] : a0[3];
            // pre-scaled gates: raw v_exp_f32
            const float A  = 1.0f + EXP2F(m0);
            const float F  = 1.0f + EXP2F(m1);
            const float Bv = 1.0f + EXP2F(m2);
            const float C  = 1.0f + EXP2F(m3);
            c_me = RCPF(F) * c_me + (Bv - 2.0f) * RCPF(A * Bv);
            const float D = 1.0f + EXP2F(c_me * (2.0f * LOG2E));
            const float h1v = (D - 2.0f) * RCPF(C * D);
            if (valid_upd) {
                u1wp[pn][4 + u_me] = (f16)h1v;
                u2wp[pr][u_me] = (f16)fmaxf(h1v, 0.0f);
            }
            // ---------- out store for t=s-2 (wave 3) ----------
            if (wv == 3 && s >= 2) {
                float v = fcw[pn][lane];            // lane = wa*8 + b
                v += __shfl_xor(v, 8);
                v += __shfl_xor(v, 16);
                v += __shfl_xor(v, 32);
                if (lane < BB) out[(size_t)(s - 2) * BATCH + bbase + lane] = v + bfc;
            }
        } else {
            // ---------- x(s+1) prefetch (wave 8) ----------
            float4 xr;
            if (wv == 8 && lane < BB) {
                const int tn = (s + 1 < SEQ) ? s + 1 : SEQ - 1;
                xr = *reinterpret_cast<const float4*>(
                    x + ((size_t)tn * BATCH + bbase + lane) * 4);
            }
            // ---------- L2 gates(t=s-1), packed lane-local update + FC ----------
            const f16* u2r = u2rp[pn];
            const v8h C0 = *reinterpret_cast<const v8h*>(&u2r[q * 8]);
            const v8h C1 = *reinterpret_cast<const v8h*>(&u2r[32 + q * 8]);
            const v8h C2 = *reinterpret_cast<const v8h*>(&u2r[64 + q * 8]);
            const v8h C3 = *reinterpret_cast<const v8h*>(&u2r[96 + q * 8]);
            v4f a0 = {0.f, 0.f, 0.f, 0.f}, a1 = {0.f, 0.f, 0.f, 0.f};
            a0 = __builtin_amdgcn_mfma_f32_16x16x32_f16(Af[0][0], C0, a0, 0, 0, 0);
            a0 = __builtin_amdgcn_mfma_f32_16x16x32_f16(Af[0][1], C1, a0, 0, 0, 0);
            a0 = __builtin_amdgcn_mfma_f32_16x16x32_f16(Af[0][2], C2, a0, 0, 0, 0);
            a0 = __builtin_amdgcn_mfma_f32_16x16x32_f16(Af[0][3], C3, a0, 0, 0, 0);
            if (wa < NT - 8) {
                a1 = __builtin_amdgcn_mfma_f32_16x16x32_f16(Af[1][0], C0, a1, 0, 0, 0);
                a1 = __builtin_amdgcn_mfma_f32_16x16x32_f16(Af[1][1], C1, a1, 0, 0, 0);
                a1 = __builtin_amdgcn_mfma_f32_16x16x32_f16(Af[1][2], C2, a1, 0, 0, 0);
                a1 = __builtin_amdgcn_mfma_f32_16x16x32_f16(Af[1][3], C3, a1, 0, 0, 0);
            }
            const float m0 = hiHalf ? a1[0] : a0[0];
            const float m1 = hiHalf ? a1[1] : a0[1];
            const float m2 = hiHalf ? a1[2] : a0[2];
            const float m3 = hiHalf ? a1[3] : a0[3];
            const float A  = 1.0f + EXP2F(m0);
            const float F  = 1.0f + EXP2F(m1);
            const float Bv = 1.0f + EXP2F(m2);
            const float C  = 1.0f + EXP2F(m3);
            const float cn = RCPF(F) * c_me + (Bv - 2.0f) * RCPF(A * Bv);
            const float D = 1.0f + EXP2F(cn * (2.0f * LOG2E));
            const float h2v = (D - 2.0f) * RCPF(C * D);
            float p = 0.0f;
            if (s >= 1) {                       // t=s-1 valid
                c_me = cn;
                if (valid_upd) u2wp[pr][HID + u_me] = (f16)h2v;
                p = fmaxf(h2v, 0.0f) * wfc_me;  // wfc_me=0 on invalid lanes
            }
            p += __shfl_xor(p, 8);              // merge tile pair (same batch)
            p += __shfl_xor(p, 16);             // merge quads
            p += __shfl_xor(p, 32);
            if (s >= 1 && lane < BB) fcw[pr][wa * BB + lane] = p;
            if (wv == 8 && lane < BB) {   // x(s+1) into next-parity u1
                f16 pk[4] = {(f16)xr.x, (f16)xr.y, (f16)xr.z, (f16)xr.w};
                *reinterpret_cast<uint2*>(&u1h[pn][lane * S1H]) = *reinterpret_cast<uint2*>(pk);
            }
        }
        __syncthreads();   // the ONE barrier per superstep
    };

    // ---- pipelined supersteps, unrolled x2 (SEQ+2 = 514 is even) ----
#pragma unroll 1
    for (int s = 0; s < SEQ + 2; s += 2) {
        body(s, 0, 1);
        body(s + 1, 1, 0);
    }
}

extern "C" void kernel_launch(void* const* d_in, const int* in_sizes, int n_in,
                              void* d_out, int out_size, void* d_ws, size_t ws_size,
                              hipStream_t stream) {
    const float* X    = (const float*)d_in[0];
    const float* Wih1 = (const float*)d_in[1];
    const float* Whh1 = (const float*)d_in[2];
    const float* Bih1 = (const float*)d_in[3];
    const float* Bhh1 = (const float*)d_in[4];
    const float* Wih2 = (const float*)d_in[5];
    const float* Whh2 = (const float*)d_in[6];
    const float* Bih2 = (const float*)d_in[7];
    const float* Bhh2 = (const float*)d_in[8];
    const float* Wfc  = (const float*)d_in[9];
    const float* Bfc  = (const float*)d_in[10];
    float* out = (float*)d_out;

    lstm2_fused<<<dim3(NBLK), dim3(NTHR), 0, stream>>>(
        X, Wih1, Whh1, Bih1, Bhh1, Wih2, Whh2, Bih2, Bhh2, Wfc, Bfc, out);
}